// Round 1
// baseline (74.863 us; speedup 1.0000x reference)
//
#include <hip/hip_runtime.h>
#include <hip/hip_bf16.h>

using f32x4 = __attribute__((ext_vector_type(4))) float;
using s16x8 = __attribute__((ext_vector_type(8))) short;

constexpr int KDIM = 768;
constexpr int NDIM = 768;
constexpr int BM = 128;
constexpr int BN = 128;
constexpr int BK = 32;
constexpr int KLD = BK + 8;    // padded LDS leading dim: 40 elems = 80 B = 20 banks -> 2-way (free)
constexpr int NT = KDIM / BK;  // 24 k-tiles

__device__ __forceinline__ short f2bf(float f) {
    unsigned u = __builtin_bit_cast(unsigned, f);
    u += 0x7FFFu + ((u >> 16) & 1u);       // round-to-nearest-even
    return (short)(unsigned short)(u >> 16);
}

__device__ __forceinline__ short sgnbf(float w) {
    // sign(w) as bf16: +1 -> 0x3F80, -1 -> 0xBF80, 0 -> 0
    return w > 0.f ? (short)(unsigned short)0x3F80u
                   : (w < 0.f ? (short)(unsigned short)0xBF80u : (short)0);
}

__device__ __forceinline__ s16x8 cvt8(float4 u, float4 v) {
    s16x8 r;
    r[0] = f2bf(u.x); r[1] = f2bf(u.y); r[2] = f2bf(u.z); r[3] = f2bf(u.w);
    r[4] = f2bf(v.x); r[5] = f2bf(v.y); r[6] = f2bf(v.z); r[7] = f2bf(v.w);
    return r;
}

__device__ __forceinline__ s16x8 sgn8(float4 u, float4 v) {
    s16x8 r;
    r[0] = sgnbf(u.x); r[1] = sgnbf(u.y); r[2] = sgnbf(u.z); r[3] = sgnbf(u.w);
    r[4] = sgnbf(v.x); r[5] = sgnbf(v.y); r[6] = sgnbf(v.z); r[7] = sgnbf(v.w);
    return r;
}

__global__ __launch_bounds__(256, 2)
void binlin_mfma(const float* __restrict__ X, const float* __restrict__ W,
                 float* __restrict__ Out, int M) {
    __shared__ __align__(16) unsigned short As[2][BM][KLD];
    __shared__ __align__(16) unsigned short Bs[2][BN][KLD];

    const int nbn = NDIM / BN;   // 6
    const int nwg = gridDim.x;   // 1536 (divisible by 8)
    const int bid = blockIdx.x;
    // XCD-aware swizzle: each XCD gets a contiguous chunk; bn iterates fastest
    // within a chunk so consecutive blocks share the A panel (L2 reuse).
    const int cpx = nwg >> 3;
    const int swz = (bid & 7) * cpx + (bid >> 3);
    const int bm = swz / nbn;
    const int bn = swz - bm * nbn;

    const int t    = threadIdx.x;
    const int lane = t & 63;
    const int wid  = t >> 6;            // 4 waves, 2x2 over the 128x128 tile
    const int wm   = (wid >> 1) * 64;
    const int wn   = (wid & 1) * 64;
    const int lr   = lane & 15;
    const int lk   = (lane >> 4) * 8;   // k-group within the 16x16x32 fragment

    const float* Xb = X + (size_t)bm * BM * KDIM;
    const float* Wb = W + (size_t)bn * BN * KDIM;  // W is [N][K] == B^T layout

    // staging decomposition: thread t owns rows r0 and r0+64, k-chunk c0..c0+7
    const int r0 = t >> 2;
    const int c0 = (t & 3) * 8;

    f32x4 acc[4][4] = {};

    // ---- prologue: stage k-tile 0 into buffer 0 ----
    {
        const float* xa  = Xb + (size_t)r0 * KDIM + c0;
        const float* xa2 = xa + (size_t)64 * KDIM;
        float4 a0 = *(const float4*)xa;
        float4 a1 = *(const float4*)(xa + 4);
        float4 a2 = *(const float4*)xa2;
        float4 a3 = *(const float4*)(xa2 + 4);
        const float* wa  = Wb + (size_t)r0 * KDIM + c0;
        const float* wa2 = wa + (size_t)64 * KDIM;
        float4 b0 = *(const float4*)wa;
        float4 b1 = *(const float4*)(wa + 4);
        float4 b2 = *(const float4*)wa2;
        float4 b3 = *(const float4*)(wa2 + 4);

        *(s16x8*)&As[0][r0][c0]      = cvt8(a0, a1);
        *(s16x8*)&As[0][r0 + 64][c0] = cvt8(a2, a3);
        *(s16x8*)&Bs[0][r0][c0]      = sgn8(b0, b1);
        *(s16x8*)&Bs[0][r0 + 64][c0] = sgn8(b2, b3);
    }
    __syncthreads();

    for (int kt = 0; kt < NT; ++kt) {
        const int buf = kt & 1;
        const bool pf = (kt + 1 < NT);

        // async-STAGE split: issue next tile's global loads first (hide HBM
        // latency under the MFMA phase), ds_write them after compute.
        float4 a0, a1, a2, a3, b0, b1, b2, b3;
        if (pf) {
            const float* xa  = Xb + (size_t)r0 * KDIM + (kt + 1) * BK + c0;
            const float* xa2 = xa + (size_t)64 * KDIM;
            a0 = *(const float4*)xa;
            a1 = *(const float4*)(xa + 4);
            a2 = *(const float4*)xa2;
            a3 = *(const float4*)(xa2 + 4);
            const float* wa  = Wb + (size_t)r0 * KDIM + (kt + 1) * BK + c0;
            const float* wa2 = wa + (size_t)64 * KDIM;
            b0 = *(const float4*)wa;
            b1 = *(const float4*)(wa + 4);
            b2 = *(const float4*)wa2;
            b3 = *(const float4*)(wa2 + 4);
        }

        // LDS -> fragments -> MFMA
        s16x8 af[4], bfr[4];
        #pragma unroll
        for (int m = 0; m < 4; ++m)
            af[m] = *(const s16x8*)&As[buf][wm + m * 16 + lr][lk];
        #pragma unroll
        for (int n = 0; n < 4; ++n)
            bfr[n] = *(const s16x8*)&Bs[buf][wn + n * 16 + lr][lk];
        #pragma unroll
        for (int m = 0; m < 4; ++m)
            #pragma unroll
            for (int n = 0; n < 4; ++n)
                acc[m][n] = __builtin_amdgcn_mfma_f32_16x16x32_bf16(
                    af[m], bfr[n], acc[m][n], 0, 0, 0);

        if (pf) {
            const int nb = buf ^ 1;
            *(s16x8*)&As[nb][r0][c0]      = cvt8(a0, a1);
            *(s16x8*)&As[nb][r0 + 64][c0] = cvt8(a2, a3);
            *(s16x8*)&Bs[nb][r0][c0]      = sgn8(b0, b1);
            *(s16x8*)&Bs[nb][r0 + 64][c0] = sgn8(b2, b3);
        }
        __syncthreads();
    }

    // ---- epilogue: C/D layout col = lane&15, row = (lane>>4)*4 + reg ----
    float* Ob = Out + (size_t)(bm * BM) * NDIM + bn * BN;
    #pragma unroll
    for (int m = 0; m < 4; ++m) {
        const int row0 = wm + m * 16 + (lane >> 4) * 4;
        #pragma unroll
        for (int n = 0; n < 4; ++n) {
            const int col = wn + n * 16 + lr;
            #pragma unroll
            for (int r = 0; r < 4; ++r)
                Ob[(size_t)(row0 + r) * NDIM + col] = acc[m][n][r];
        }
    }
}

extern "C" void kernel_launch(void* const* d_in, const int* in_sizes, int n_in,
                              void* d_out, int out_size, void* d_ws, size_t ws_size,
                              hipStream_t stream) {
    const float* X = (const float*)d_in[0];
    const float* W = (const float*)d_in[1];
    float* Out = (float*)d_out;
    const int M = in_sizes[0] / KDIM;   // 4*8192 = 32768
    const int grid = (M / BM) * (NDIM / BN);  // 256 * 6 = 1536
    binlin_mfma<<<grid, 256, 0, stream>>>(X, W, Out, M);
}